// Round 16
// baseline (57.422 us; speedup 1.0000x reference)
//
#include <hip/hip_runtime.h>
#include <hip/hip_bf16.h>

#define HEADS 8
#define DK 32
#define DV 64
#define DIM 256
#define NCTX 1024
#define NB 8
#define IDK 256
#define IDV 512
#define SCALE 0.17677669529663687f
#define INV_SCALE 5.656854249492381f
#define LOG2E 1.4426950408889634f
#define BN_EPS 1e-5f
#define THR 11.5416f   /* 8 * log2e : defer-max threshold in log2 domain */

typedef __bf16 bf16x8 __attribute__((ext_vector_type(8)));
typedef __bf16 bf16x4 __attribute__((ext_vector_type(4)));
typedef float f32x4 __attribute__((ext_vector_type(4)));
typedef float f32x16 __attribute__((ext_vector_type(16)));

static __device__ __forceinline__ unsigned short bfbits(float v) {
  __bf16 b = (__bf16)v;
  return __builtin_bit_cast(unsigned short, b);
}

// ---------------- prep (weights+bias+8-packed bias-table) U transpose ----------
// Tq8g[h][t] (uint4 = 8 bf16): elem e = biasv(t - 8*(e>>2) - (e&3)),
// biasv(u) = pe_h[|u-1023|]*INV_SCALE*LOG2E. One b128 read covers 2 q-slots.
__global__ __launch_bounds__(256) void k_prep_trans(
    const float* __restrict__ x,
    const float* __restrict__ Wq, const float* __restrict__ Wk,
    const float* __restrict__ Wv, const float* __restrict__ Wo,
    const float* __restrict__ bo, const float* __restrict__ pe,
    const float* __restrict__ qg, const float* __restrict__ qb,
    const float* __restrict__ qm, const float* __restrict__ qv,
    const float* __restrict__ kg, const float* __restrict__ kb,
    const float* __restrict__ km, const float* __restrict__ kv,
    const float* __restrict__ vg, const float* __restrict__ vb,
    const float* __restrict__ vm, const float* __restrict__ vv,
    const float* __restrict__ og, const float* __restrict__ ob,
    const float* __restrict__ om, const float* __restrict__ ov,
    __bf16* __restrict__ xT, __bf16* __restrict__ WB, float* __restrict__ BB,
    uint4* __restrict__ Tq8g) {
  int bid = blockIdx.x;
  if (bid < 1605) {
    int idx = bid * 256 + threadIdx.x;
    if (idx < 65536) {
      int o = idx >> 8;
      WB[idx] = (__bf16)(Wq[idx] * (qg[o] * rsqrtf(qv[o] + BN_EPS) * SCALE * LOG2E));
    } else if (idx < 131072) {
      int i = idx - 65536, o = i >> 8;
      WB[idx] = (__bf16)(Wk[i] * (kg[o] * rsqrtf(kv[o] + BN_EPS)));
    } else if (idx < 262144) {
      int i = idx - 131072, o = i >> 8;
      WB[idx] = (__bf16)(Wv[i] * (vg[o] * rsqrtf(vv[o] + BN_EPS)));
    } else if (idx < 393216) {
      int i = idx - 262144, o = i >> 9;
      WB[idx] = (__bf16)(Wo[i] * (og[o] * rsqrtf(ov[o] + BN_EPS)));
    } else if (idx < 394496) {
      int i = idx - 393216;
      if (i < 256) {
        float sc = qg[i] * rsqrtf(qv[i] + BN_EPS);
        BB[i] = (qb[i] - qm[i] * sc) * SCALE * LOG2E;
      } else if (i < 512) {
        int o = i - 256;
        float sc = kg[o] * rsqrtf(kv[o] + BN_EPS);
        BB[i] = kb[o] - km[o] * sc;
      } else if (i < 1024) {
        int o = i - 512;
        float sc = vg[o] * rsqrtf(vv[o] + BN_EPS);
        BB[i] = vb[o] - vm[o] * sc;
      } else {
        int o = i - 1024;
        float sc = og[o] * rsqrtf(ov[o] + BN_EPS);
        BB[i] = (bo[o] - om[o]) * sc + ob[o];
      }
    } else {
      int i = idx - 394496;          // 8 * 2048 entries
      int h = i >> 11, t = i & 2047;
      unsigned short us[8];
#pragma unroll
      for (int e = 0; e < 8; ++e) {
        int d = t - 8 * (e >> 2) - (e & 3) - 1023;
        d = d < 0 ? -d : d; d = d > 1023 ? 1023 : d;
        us[e] = bfbits(pe[(size_t)d * HEADS + h] * INV_SCALE * LOG2E);
      }
      uint4 ev;
      ev.x = (unsigned)us[0] | ((unsigned)us[1] << 16);
      ev.y = (unsigned)us[2] | ((unsigned)us[3] << 16);
      ev.z = (unsigned)us[4] | ((unsigned)us[5] << 16);
      ev.w = (unsigned)us[6] | ((unsigned)us[7] << 16);
      Tq8g[((size_t)h << 11) + t] = ev;
    }
  } else {
    // transpose x[b,c,n] f32 -> xT[b,n,c] bf16
    __shared__ float t[64][65];
    int tb = bid - 1605;
    int b = tb >> 6, c0 = ((tb >> 4) & 3) * 64, n0 = (tb & 15) * 64;
    int col = threadIdx.x & 63, rb = threadIdx.x >> 6;
    const float* xp = x + ((size_t)b * DIM + c0) * NCTX + n0;
#pragma unroll
    for (int r = 0; r < 16; ++r) {
      int row = rb + 4 * r;
      t[row][col] = xp[(size_t)row * NCTX + col];
    }
    __syncthreads();
    __bf16* op = xT + ((size_t)b * NCTX + n0) * DIM + c0;
#pragma unroll
    for (int r = 0; r < 16; ++r) {
      int i = rb + 4 * r;
      op[(size_t)i * DIM + col] = (__bf16)t[col][i];
    }
  }
}

// ---------------- QKV GEMM: 128x128 block, XOR-swizzled LDS, packed stores ----
__global__ __launch_bounds__(256, 2) void k_gemm_qkv(
    const __bf16* __restrict__ Xsrc, const __bf16* __restrict__ Wsrc,
    const float* __restrict__ Bias, __bf16* __restrict__ Qws,
    __bf16* __restrict__ Kws, __bf16* __restrict__ Vws) {
  int bx = blockIdx.x, by = blockIdx.y;
  int mode = by < 2 ? 0 : (by < 4 ? 1 : 2);
  int tid = threadIdx.x, wave = tid >> 6, lane = tid & 63;
  int wm = wave >> 1, wn = wave & 1;
  int l16 = lane & 15, g = (lane >> 4) & 3, g4 = g * 4;
  int R0 = bx * 128;

  __shared__ __align__(16) char XTl[16384];
  __shared__ __align__(16) char WTl[16384];

  int sr = tid >> 1, sh = tid & 1;
  const __bf16* xg = Xsrc + (size_t)(R0 + sr) * DIM + sh * 32;
  const __bf16* wg = Wsrc + (size_t)(by * 128 + sr) * DIM + sh * 32;
  int wbase = sr * 128;
  int gsw[4];
#pragma unroll
  for (int q = 0; q < 4; ++q) gsw[q] = ((sh * 4 + q) ^ (sr & 7)) * 16;

  bf16x8 sx[4], sw[4];
#pragma unroll
  for (int q = 0; q < 4; ++q) {
    sx[q] = *reinterpret_cast<const bf16x8*>(xg + q * 8);
    sw[q] = *reinterpret_cast<const bf16x8*>(wg + q * 8);
  }

  f32x4 acc[4][4] = {};
  const char* Abase = (mode <= 1) ? WTl : XTl;
  const char* Bbase = (mode <= 1) ? XTl : WTl;

  for (int st = 0; st < 4; ++st) {
    __syncthreads();
#pragma unroll
    for (int q = 0; q < 4; ++q) {
      *reinterpret_cast<bf16x8*>(XTl + wbase + gsw[q]) = sx[q];
      *reinterpret_cast<bf16x8*>(WTl + wbase + gsw[q]) = sw[q];
    }
    __syncthreads();
    if (st + 1 < 4) {
      const __bf16* xn = xg + (st + 1) * 64;
      const __bf16* wn_ = wg + (st + 1) * 64;
#pragma unroll
      for (int q = 0; q < 4; ++q) {
        sx[q] = *reinterpret_cast<const bf16x8*>(xn + q * 8);
        sw[q] = *reinterpret_cast<const bf16x8*>(wn_ + q * 8);
      }
    }
#pragma unroll
    for (int kc = 0; kc < 2; ++kc) {
      bf16x8 af[4], bf[4];
#pragma unroll
      for (int t = 0; t < 4; ++t) {
        int ra = wm * 64 + t * 16 + l16;
        af[t] = *reinterpret_cast<const bf16x8*>(
            Abase + ra * 128 + (((kc * 4 + g) ^ (ra & 7)) * 16));
        int rb = wn * 64 + t * 16 + l16;
        bf[t] = *reinterpret_cast<const bf16x8*>(
            Bbase + rb * 128 + (((kc * 4 + g) ^ (rb & 7)) * 16));
      }
      __builtin_amdgcn_s_setprio(1);
#pragma unroll
      for (int mt = 0; mt < 4; ++mt)
#pragma unroll
        for (int nt = 0; nt < 4; ++nt)
          acc[mt][nt] = __builtin_amdgcn_mfma_f32_16x16x32_bf16(
              af[mt], bf[nt], acc[mt][nt], 0, 0, 0);
      __builtin_amdgcn_s_setprio(0);
    }
  }

  if (mode <= 1) {  // Q/K: acc[m=o][n=i]; pack 4 consecutive d -> b64
    __bf16* OWS = (mode == 0) ? Qws : Kws;
    const float* bb = Bias + (mode == 0 ? 0 : 256);
    int oq0 = by * 128 - (mode == 1 ? 256 : 0) + wm * 64;
#pragma unroll
    for (int mt = 0; mt < 4; ++mt) {
      int oq = oq0 + mt * 16 + g4;
      float4 b4 = *reinterpret_cast<const float4*>(&bb[oq]);
      int h = oq >> 5, d0 = oq & 31;
#pragma unroll
      for (int nt = 0; nt < 4; ++nt) {
        int i = R0 + wn * 64 + nt * 16 + l16;
        int b = i >> 10, n = i & 1023;
        bf16x4 pk;
        pk[0] = (__bf16)(acc[mt][nt][0] + b4.x);
        pk[1] = (__bf16)(acc[mt][nt][1] + b4.y);
        pk[2] = (__bf16)(acc[mt][nt][2] + b4.z);
        pk[3] = (__bf16)(acc[mt][nt][3] + b4.w);
        *reinterpret_cast<bf16x4*>(
            &OWS[(((size_t)b * HEADS + h) * NCTX + n) * DK + d0]) = pk;
      }
    }
  } else {  // V: acc[m=i][n=vo]; pack 4 consecutive n -> b64
#pragma unroll
    for (int nt = 0; nt < 4; ++nt) {
      int vo = (by - 4) * 128 + wn * 64 + nt * 16 + l16;
      float bia = Bias[512 + vo];
#pragma unroll
      for (int mt = 0; mt < 4; ++mt) {
        int i0 = R0 + wm * 64 + mt * 16 + g4;
        int b = i0 >> 10, n = i0 & 1023;
        bf16x4 pk;
#pragma unroll
        for (int rr = 0; rr < 4; ++rr) pk[rr] = (__bf16)(acc[mt][nt][rr] + bia);
        *reinterpret_cast<bf16x4*>(&Vws[((size_t)b * IDV + vo) * NCTX + n]) = pk;
      }
    }
  }
}

// ---------------- out-proj GEMM: 64x64 tiles -> grid 512 (2 blocks/CU) ---------
__global__ __launch_bounds__(256, 4) void k_gemm_out(
    const __bf16* __restrict__ G, const __bf16* __restrict__ WoB,
    const float* __restrict__ bo2, float* __restrict__ out) {
  int bx = blockIdx.x, by = blockIdx.y;   // bx<128, by<4
  int tid = threadIdx.x, wave = tid >> 6, lane = tid & 63;
  int wm = wave >> 1, wn = wave & 1;
  int l16 = lane & 15, g = (lane >> 4) & 3, g4 = g * 4;
  int R0 = bx * 64;

  __shared__ __align__(16) char XTl[8192];   // 64 rows x 64 bf16 (128B rows)
  __shared__ __align__(16) char WTl[8192];   // 64 rows x 64 bf16

  int sr = tid >> 2, sq = tid & 3;
  const __bf16* xg = G + (size_t)(R0 + sr) * IDV + sq * 16;
  const __bf16* wg = WoB + (size_t)(by * 64 + sr) * IDV + sq * 16;
  int sbase = sr * 128;
  int gswq[2];
#pragma unroll
  for (int q = 0; q < 2; ++q) gswq[q] = ((sq * 2 + q) ^ (sr & 7)) * 16;

  bf16x8 sx[2], sw[2];
#pragma unroll
  for (int q = 0; q < 2; ++q) {
    sx[q] = *reinterpret_cast<const bf16x8*>(xg + q * 8);
    sw[q] = *reinterpret_cast<const bf16x8*>(wg + q * 8);
  }

  f32x4 acc[2][2] = {};

  for (int st = 0; st < 8; ++st) {
    __syncthreads();
#pragma unroll
    for (int q = 0; q < 2; ++q) {
      *reinterpret_cast<bf16x8*>(XTl + sbase + gswq[q]) = sx[q];
      *reinterpret_cast<bf16x8*>(WTl + sbase + gswq[q]) = sw[q];
    }
    __syncthreads();
    if (st + 1 < 8) {
      const __bf16* xn = xg + (st + 1) * 64;
      const __bf16* wn_ = wg + (st + 1) * 64;
#pragma unroll
      for (int q = 0; q < 2; ++q) {
        sx[q] = *reinterpret_cast<const bf16x8*>(xn + q * 8);
        sw[q] = *reinterpret_cast<const bf16x8*>(wn_ + q * 8);
      }
    }
#pragma unroll
    for (int kc = 0; kc < 2; ++kc) {
      bf16x8 af[2], bf[2];
#pragma unroll
      for (int t = 0; t < 2; ++t) {
        int ra = wm * 32 + t * 16 + l16;
        af[t] = *reinterpret_cast<const bf16x8*>(
            XTl + ra * 128 + (((kc * 4 + g) ^ (ra & 7)) * 16));
        int rb = wn * 32 + t * 16 + l16;
        bf[t] = *reinterpret_cast<const bf16x8*>(
            WTl + rb * 128 + (((kc * 4 + g) ^ (rb & 7)) * 16));
      }
      __builtin_amdgcn_s_setprio(1);
#pragma unroll
      for (int mt = 0; mt < 2; ++mt)
#pragma unroll
        for (int nt = 0; nt < 2; ++nt)
          acc[mt][nt] = __builtin_amdgcn_mfma_f32_16x16x32_bf16(
              af[mt], bf[nt], acc[mt][nt], 0, 0, 0);
      __builtin_amdgcn_s_setprio(0);
    }
  }
#pragma unroll
  for (int nt = 0; nt < 2; ++nt) {
    int o = by * 64 + wn * 32 + nt * 16 + l16;
    float bia = bo2[o];
#pragma unroll
    for (int mt = 0; mt < 2; ++mt) {
      int i0 = R0 + wm * 32 + mt * 16 + g4;
      int b = i0 >> 10, n = i0 & 1023;
      float4 st;
      st.x = acc[mt][nt][0] + bia;
      st.y = acc[mt][nt][1] + bia;
      st.z = acc[mt][nt][2] + bia;
      st.w = acc[mt][nt][3] + bia;
      *reinterpret_cast<float4*>(&out[((size_t)b * DIM + o) * NCTX + n]) = st;
    }
  }
}

// ---------------- attention: R9 skeleton + 8-packed bias (b128 reads) ----------
// 128 rows/block, 4 waves, K+V LDS dbuf, 1 barrier/iter. Bias: 4 b128/iter
// (was 8 b64) -> per-iter DS instrs 23 -> 19. LDS 44.6 KB -> 3 blocks/CU.
__global__ __launch_bounds__(256, 3) void k_attn(
    const __bf16* __restrict__ Qws, const __bf16* __restrict__ Kws,
    const __bf16* __restrict__ Vws, const uint4* __restrict__ Tq8g,
    __bf16* __restrict__ G) {
  int flat = blockIdx.x;                       // 512
  int swz = (flat & 7) * 64 + (flat >> 3);     // XCD-aware: 64 consecutive ids/XCD
  int iblk = swz & 7, bh = swz >> 3;
  int b = bh >> 3, h = bh & 7;
  int tid = threadIdx.x, wave = tid >> 6, lane = tid & 63;
  int l31 = lane & 31, hi = lane >> 5;

  __shared__ __align__(16) __bf16 Klds[2][64][40];
  __shared__ __align__(16) __bf16 Vlds[2][64 * 64];
  __shared__ __align__(16) uint4 TqL[1152];

  int i0b = iblk * 128;
  {
    const uint4* tg4 = Tq8g + ((size_t)h << 11) + i0b;
    for (int c = tid; c < 1152; c += 256) TqL[c] = tg4[c];
  }

  int i0w = i0b + wave * 32;
  int irow = i0w + l31;
  const __bf16* qbase = Qws + (size_t)bh * NCTX * DK;
  const __bf16* kbase = Kws + (size_t)bh * NCTX * DK;
  const __bf16* vbase = Vws + ((size_t)b * IDV + h * DV) * NCTX;
  bf16x8 qf0 = *reinterpret_cast<const bf16x8*>(qbase + (size_t)irow * DK + 8 * hi);
  bf16x8 qf1 = *reinterpret_cast<const bf16x8*>(qbase + (size_t)irow * DK + 16 + 8 * hi);

  // staging map: thread -> K row r_ slot sk (1 granule); V row r_ slots sk, sk+4
  int r_ = tid >> 2, sk = tid & 3;
  const __bf16* kgp = kbase + (size_t)r_ * DK + 8 * sk;
  const __bf16* vgp = vbase + (size_t)r_ * NCTX + 8 * sk;
  int ko = r_ * 40 + 8 * sk;
  int vo0 = r_ * 64 + 8 * (sk ^ (r_ & 7));
  int vo1 = r_ * 64 + 8 * ((sk + 4) ^ (r_ & 7));

  // prologue: tile 0 -> buf 0
  bf16x8 rk = *reinterpret_cast<const bf16x8*>(kgp);
  bf16x8 rv0 = *reinterpret_cast<const bf16x8*>(vgp);
  bf16x8 rv1 = *reinterpret_cast<const bf16x8*>(vgp + 32);
  *reinterpret_cast<bf16x8*>(&Klds[0][0][0] + ko) = rk;
  *reinterpret_cast<bf16x8*>(&Vlds[0][0] + vo0) = rv0;
  *reinterpret_cast<bf16x8*>(&Vlds[0][0] + vo1) = rv1;

  f32x16 acc0 = {}, acc1 = {};
  float m = -1e30f, s = 0.0f;
  int kxb = wave * 32 + l31 + 1023 - 4 * hi;
  const bf16x8* Tqp = reinterpret_cast<const bf16x8*>(TqL);

  __syncthreads();   // buf0 + TqL visible

  for (int it = 0; it < 16; ++it) {
    int cur = it & 1, nxt = cur ^ 1;
    int j0 = it * 64;
    // issue next-tile loads early: they fly across this iteration's compute
    int jn = (j0 + 64) & (NCTX - 1);
    rk = *reinterpret_cast<const bf16x8*>(kgp + (size_t)jn * DK);
    rv0 = *reinterpret_cast<const bf16x8*>(vgp + jn);
    rv1 = *reinterpret_cast<const bf16x8*>(vgp + jn + 32);

    // ---- compute from buf[cur] ----
    float sv[32];
#pragma unroll
    for (int jg = 0; jg < 2; ++jg) {
      bf16x8 kf0 = *reinterpret_cast<const bf16x8*>(&Klds[cur][32 * jg + l31][8 * hi]);
      bf16x8 kf1 = *reinterpret_cast<const bf16x8*>(&Klds[cur][32 * jg + l31][16 + 8 * hi]);
      f32x16 S = {};
      __builtin_amdgcn_s_setprio(1);
      S = __builtin_amdgcn_mfma_f32_32x32x16_bf16(kf0, qf0, S, 0, 0, 0);
      S = __builtin_amdgcn_mfma_f32_32x32x16_bf16(kf1, qf1, S, 0, 0, 0);
      __builtin_amdgcn_s_setprio(0);
      int kb_ = kxb - j0 - 32 * jg;
      bf16x8 e8a = Tqp[kb_];        // q = 0,1
      bf16x8 e8b = Tqp[kb_ - 16];   // q = 2,3
#pragma unroll
      for (int e = 0; e < 8; ++e) {
        sv[jg * 16 + e] = S[e] + (float)e8a[e];
        sv[jg * 16 + 8 + e] = S[8 + e] + (float)e8b[e];
      }
    }
    float pmax = sv[0];
#pragma unroll
    for (int k = 1; k < 32; ++k) pmax = fmaxf(pmax, sv[k]);
    if (__any(pmax > m + THR)) {   // rare after first tile
      float mx = fmaxf(pmax, __shfl_xor(pmax, 32));
      float mnew = fmaxf(m, mx);
      float corr = __builtin_amdgcn_exp2f(m - mnew);
      s *= corr; m = mnew;
#pragma unroll
      for (int r = 0; r < 16; ++r) {
        float cv = __shfl(corr, (r & 3) + 8 * (r >> 2) + 4 * hi);
        acc0[r] *= cv; acc1[r] *= cv;
      }
    }
#pragma unroll
    for (int k = 0; k < 32; ++k) sv[k] = __builtin_amdgcn_exp2f(sv[k] - m);
    float ps = 0.0f;
#pragma unroll
    for (int k = 0; k < 32; ++k) ps += sv[k];
    s += ps;
#pragma unroll
    for (int jg = 0; jg < 2; ++jg) {
#pragma unroll
      for (int u = 0; u < 2; ++u) {
        int base = jg * 16 + 8 * u;
        unsigned we0, we1, wo0, wo1;
        asm("v_cvt_pk_bf16_f32 %0, %1, %2" : "=v"(we0) : "v"(sv[base + 0]), "v"(sv[base + 1]));
        asm("v_cvt_pk_bf16_f32 %0, %1, %2" : "=v"(we1) : "v"(sv[base + 2]), "v"(sv[base + 3]));
        asm("v_cvt_pk_bf16_f32 %0, %1, %2" : "=v"(wo0) : "v"(sv[base + 4]), "v"(sv[base + 5]));
        asm("v_cvt_pk_bf16_f32 %0, %1, %2" : "=v"(wo1) : "v"(sv[base + 6]), "v"(sv[base + 7]));
        asm volatile("v_permlane32_swap_b32 %0, %1" : "+v"(we0), "+v"(wo0));
        asm volatile("v_permlane32_swap_b32 %0, %1" : "+v"(we1), "+v"(wo1));
        uint4 pw = {we0, we1, wo0, wo1};
        bf16x8 pfrag = *reinterpret_cast<bf16x8*>(&pw);
        int sl = 2 * (jg * 2 + u) + hi;
        bf16x8 vf0 = *reinterpret_cast<const bf16x8*>(
            &Vlds[cur][0] + l31 * 64 + 8 * (sl ^ (l31 & 7)));
        bf16x8 vf1 = *reinterpret_cast<const bf16x8*>(
            &Vlds[cur][0] + (32 + l31) * 64 + 8 * (sl ^ (l31 & 7)));
        __builtin_amdgcn_s_setprio(1);
        acc0 = __builtin_amdgcn_mfma_f32_32x32x16_bf16(pfrag, vf0, acc0, 0, 0, 0);
        acc1 = __builtin_amdgcn_mfma_f32_32x32x16_bf16(pfrag, vf1, acc1, 0, 0, 0);
        __builtin_amdgcn_s_setprio(0);
      }
    }
    // ---- write tile t+1 into buf[nxt] (loads had the whole compute to land) ----
    *reinterpret_cast<bf16x8*>(&Klds[nxt][0][0] + ko) = rk;
    *reinterpret_cast<bf16x8*>(&Vlds[nxt][0] + vo0) = rv0;
    *reinterpret_cast<bf16x8*>(&Vlds[nxt][0] + vo1) = rv1;
    __syncthreads();   // single barrier per iteration
  }
  // epilogue: row-sum across hi halves, /s, exact gelu, store
  float srow = s + __shfl_xor(s, 32);
  float inv = 1.0f / srow;
  __bf16* gbase = G + (size_t)b * NCTX * IDV + h * DV + l31;
#pragma unroll
  for (int r = 0; r < 16; ++r) {
    int il = (r & 3) + 8 * (r >> 2) + 4 * hi;
    float iv = __shfl(inv, il);
    float v0 = acc0[r] * iv, v1 = acc1[r] * iv;
    float g0 = 0.5f * v0 * (1.0f + erff(v0 * 0.70710678118654752f));
    float g1 = 0.5f * v1 * (1.0f + erff(v1 * 0.70710678118654752f));
    gbase[(size_t)(i0w + il) * IDV] = (__bf16)g0;
    gbase[(size_t)(i0w + il) * IDV + 32] = (__bf16)g1;
  }
}

extern "C" void kernel_launch(void* const* d_in, const int* in_sizes, int n_in,
                              void* d_out, int out_size, void* d_ws, size_t ws_size,
                              hipStream_t stream) {
  const float* x  = (const float*)d_in[0];
  const float* Wq = (const float*)d_in[1];
  const float* Wk = (const float*)d_in[2];
  const float* Wv = (const float*)d_in[3];
  const float* Wo = (const float*)d_in[4];
  const float* bo = (const float*)d_in[5];
  const float* pe = (const float*)d_in[6];
  const float* qg = (const float*)d_in[7];
  const float* qb = (const float*)d_in[8];
  const float* qm = (const float*)d_in[9];
  const float* qv = (const float*)d_in[10];
  const float* kg = (const float*)d_in[11];
  const float* kb = (const float*)d_in[12];
  const float* km = (const float*)d_in[13];
  const float* kv = (const float*)d_in[14];
  const float* vg = (const float*)d_in[15];
  const float* vb = (const float*)d_in[16];
  const float* vm = (const float*)d_in[17];
  const float* vv = (const float*)d_in[18];
  const float* og = (const float*)d_in[19];
  const float* ob = (const float*)d_in[20];
  const float* om = (const float*)d_in[21];
  const float* ov = (const float*)d_in[22];

  char* ws = (char*)d_ws;
  __bf16* xT = (__bf16*)(ws);                       // 4 MB
  __bf16* Q  = (__bf16*)(ws + (4ull << 20));        // 4 MB
  __bf16* K  = (__bf16*)(ws + (8ull << 20));        // 4 MB
  __bf16* V  = (__bf16*)(ws + (12ull << 20));       // 8 MB
  __bf16* G  = (__bf16*)(ws + (20ull << 20));       // 8 MB
  __bf16* WB = (__bf16*)(ws + (28ull << 20));       // 768 KB bf16 weights (stacked)
  float*  BB = (float*)(ws + (28ull << 20) + (768ull << 10));  // 5 KB biases
  uint4*  Tq = (uint4*)(ws + (29ull << 20));        // 256 KB 8-packed bias table
  float* out = (float*)d_out;

  k_prep_trans<<<dim3(2117), 256, 0, stream>>>(
      x, Wq, Wk, Wv, Wo, bo, pe, qg, qb, qm, qv, kg, kb, km, kv,
      vg, vb, vm, vv, og, ob, om, ov, xT, WB, BB, Tq);
  k_gemm_qkv<<<dim3(64, 8), 256, 0, stream>>>(xT, WB, BB, Q, K, V);
  k_attn<<<dim3(512), 256, 0, stream>>>(Q, K, V, Tq, G);
  k_gemm_out<<<dim3(128, 4), 256, 0, stream>>>(G, WB + 262144, BB + 1024, out);
}

// Round 17
// 56.889 us; speedup vs baseline: 1.0094x; 1.0094x over previous
//
#include <hip/hip_runtime.h>
#include <hip/hip_bf16.h>

#define HEADS 8
#define DK 32
#define DV 64
#define DIM 256
#define NCTX 1024
#define NB 8
#define IDK 256
#define IDV 512
#define SCALE 0.17677669529663687f
#define INV_SCALE 5.656854249492381f
#define LOG2E 1.4426950408889634f
#define BN_EPS 1e-5f
#define THR 11.5416f   /* 8 * log2e : defer-max threshold in log2 domain */

typedef __bf16 bf16x8 __attribute__((ext_vector_type(8)));
typedef __bf16 bf16x4 __attribute__((ext_vector_type(4)));
typedef float f32x4 __attribute__((ext_vector_type(4)));
typedef float f32x16 __attribute__((ext_vector_type(16)));

static __device__ __forceinline__ unsigned short bfbits(float v) {
  __bf16 b = (__bf16)v;
  return __builtin_bit_cast(unsigned short, b);
}

// ---------------- prep (weights+bias+bias-table) U transpose ----------------
__global__ __launch_bounds__(256) void k_prep_trans(
    const float* __restrict__ x,
    const float* __restrict__ Wq, const float* __restrict__ Wk,
    const float* __restrict__ Wv, const float* __restrict__ Wo,
    const float* __restrict__ bo, const float* __restrict__ pe,
    const float* __restrict__ qg, const float* __restrict__ qb,
    const float* __restrict__ qm, const float* __restrict__ qv,
    const float* __restrict__ kg, const float* __restrict__ kb,
    const float* __restrict__ km, const float* __restrict__ kv,
    const float* __restrict__ vg, const float* __restrict__ vb,
    const float* __restrict__ vm, const float* __restrict__ vv,
    const float* __restrict__ og, const float* __restrict__ ob,
    const float* __restrict__ om, const float* __restrict__ ov,
    __bf16* __restrict__ xT, __bf16* __restrict__ WB, float* __restrict__ BB,
    uint2* __restrict__ Tq4g) {
  int bid = blockIdx.x;
  if (bid < 1605) {
    int idx = bid * 256 + threadIdx.x;
    if (idx < 65536) {
      int o = idx >> 8;
      WB[idx] = (__bf16)(Wq[idx] * (qg[o] * rsqrtf(qv[o] + BN_EPS) * SCALE * LOG2E));
    } else if (idx < 131072) {
      int i = idx - 65536, o = i >> 8;
      WB[idx] = (__bf16)(Wk[i] * (kg[o] * rsqrtf(kv[o] + BN_EPS)));
    } else if (idx < 262144) {
      int i = idx - 131072, o = i >> 8;
      WB[idx] = (__bf16)(Wv[i] * (vg[o] * rsqrtf(vv[o] + BN_EPS)));
    } else if (idx < 393216) {
      int i = idx - 262144, o = i >> 9;
      WB[idx] = (__bf16)(Wo[i] * (og[o] * rsqrtf(ov[o] + BN_EPS)));
    } else if (idx < 394496) {
      int i = idx - 393216;
      if (i < 256) {
        float sc = qg[i] * rsqrtf(qv[i] + BN_EPS);
        BB[i] = (qb[i] - qm[i] * sc) * SCALE * LOG2E;
      } else if (i < 512) {
        int o = i - 256;
        float sc = kg[o] * rsqrtf(kv[o] + BN_EPS);
        BB[i] = kb[o] - km[o] * sc;
      } else if (i < 1024) {
        int o = i - 512;
        float sc = vg[o] * rsqrtf(vv[o] + BN_EPS);
        BB[i] = vb[o] - vm[o] * sc;
      } else {
        int o = i - 1024;
        float sc = og[o] * rsqrtf(ov[o] + BN_EPS);
        BB[i] = (bo[o] - om[o]) * sc + ob[o];
      }
    } else {
      int i = idx - 394496;          // 8 * 2048 entries
      int h = i >> 11, t = i & 2047;
      unsigned short us[4];
#pragma unroll
      for (int rr = 0; rr < 4; ++rr) {
        int d = t - rr - 1023; d = d < 0 ? -d : d; d = d > 1023 ? 1023 : d;
        us[rr] = bfbits(pe[(size_t)d * HEADS + h] * INV_SCALE * LOG2E);
      }
      uint2 e;
      e.x = (unsigned)us[0] | ((unsigned)us[1] << 16);
      e.y = (unsigned)us[2] | ((unsigned)us[3] << 16);
      Tq4g[((size_t)h << 11) + t] = e;
    }
  } else {
    // transpose x[b,c,n] f32 -> xT[b,n,c] bf16
    __shared__ float t[64][65];
    int tb = bid - 1605;
    int b = tb >> 6, c0 = ((tb >> 4) & 3) * 64, n0 = (tb & 15) * 64;
    int col = threadIdx.x & 63, rb = threadIdx.x >> 6;
    const float* xp = x + ((size_t)b * DIM + c0) * NCTX + n0;
#pragma unroll
    for (int r = 0; r < 16; ++r) {
      int row = rb + 4 * r;
      t[row][col] = xp[(size_t)row * NCTX + col];
    }
    __syncthreads();
    __bf16* op = xT + ((size_t)b * NCTX + n0) * DIM + c0;
#pragma unroll
    for (int r = 0; r < 16; ++r) {
      int i = rb + 4 * r;
      op[(size_t)i * DIM + col] = (__bf16)t[col][i];
    }
  }
}

// ---------------- QKV GEMM: 128x128 block, XOR-swizzled LDS, packed stores ----
__global__ __launch_bounds__(256, 2) void k_gemm_qkv(
    const __bf16* __restrict__ Xsrc, const __bf16* __restrict__ Wsrc,
    const float* __restrict__ Bias, __bf16* __restrict__ Qws,
    __bf16* __restrict__ Kws, __bf16* __restrict__ Vws) {
  int bx = blockIdx.x, by = blockIdx.y;
  int mode = by < 2 ? 0 : (by < 4 ? 1 : 2);
  int tid = threadIdx.x, wave = tid >> 6, lane = tid & 63;
  int wm = wave >> 1, wn = wave & 1;
  int l16 = lane & 15, g = (lane >> 4) & 3, g4 = g * 4;
  int R0 = bx * 128;

  __shared__ __align__(16) char XTl[16384];
  __shared__ __align__(16) char WTl[16384];

  int sr = tid >> 1, sh = tid & 1;
  const __bf16* xg = Xsrc + (size_t)(R0 + sr) * DIM + sh * 32;
  const __bf16* wg = Wsrc + (size_t)(by * 128 + sr) * DIM + sh * 32;
  int wbase = sr * 128;
  int gsw[4];
#pragma unroll
  for (int q = 0; q < 4; ++q) gsw[q] = ((sh * 4 + q) ^ (sr & 7)) * 16;

  bf16x8 sx[4], sw[4];
#pragma unroll
  for (int q = 0; q < 4; ++q) {
    sx[q] = *reinterpret_cast<const bf16x8*>(xg + q * 8);
    sw[q] = *reinterpret_cast<const bf16x8*>(wg + q * 8);
  }

  f32x4 acc[4][4] = {};
  const char* Abase = (mode <= 1) ? WTl : XTl;
  const char* Bbase = (mode <= 1) ? XTl : WTl;

  for (int st = 0; st < 4; ++st) {
    __syncthreads();
#pragma unroll
    for (int q = 0; q < 4; ++q) {
      *reinterpret_cast<bf16x8*>(XTl + wbase + gsw[q]) = sx[q];
      *reinterpret_cast<bf16x8*>(WTl + wbase + gsw[q]) = sw[q];
    }
    __syncthreads();
    if (st + 1 < 4) {
      const __bf16* xn = xg + (st + 1) * 64;
      const __bf16* wn_ = wg + (st + 1) * 64;
#pragma unroll
      for (int q = 0; q < 4; ++q) {
        sx[q] = *reinterpret_cast<const bf16x8*>(xn + q * 8);
        sw[q] = *reinterpret_cast<const bf16x8*>(wn_ + q * 8);
      }
    }
#pragma unroll
    for (int kc = 0; kc < 2; ++kc) {
      bf16x8 af[4], bf[4];
#pragma unroll
      for (int t = 0; t < 4; ++t) {
        int ra = wm * 64 + t * 16 + l16;
        af[t] = *reinterpret_cast<const bf16x8*>(
            Abase + ra * 128 + (((kc * 4 + g) ^ (ra & 7)) * 16));
        int rb = wn * 64 + t * 16 + l16;
        bf[t] = *reinterpret_cast<const bf16x8*>(
            Bbase + rb * 128 + (((kc * 4 + g) ^ (rb & 7)) * 16));
      }
      __builtin_amdgcn_s_setprio(1);
#pragma unroll
      for (int mt = 0; mt < 4; ++mt)
#pragma unroll
        for (int nt = 0; nt < 4; ++nt)
          acc[mt][nt] = __builtin_amdgcn_mfma_f32_16x16x32_bf16(
              af[mt], bf[nt], acc[mt][nt], 0, 0, 0);
      __builtin_amdgcn_s_setprio(0);
    }
  }

  if (mode <= 1) {  // Q/K: acc[m=o][n=i]; pack 4 consecutive d -> b64
    __bf16* OWS = (mode == 0) ? Qws : Kws;
    const float* bb = Bias + (mode == 0 ? 0 : 256);
    int oq0 = by * 128 - (mode == 1 ? 256 : 0) + wm * 64;
#pragma unroll
    for (int mt = 0; mt < 4; ++mt) {
      int oq = oq0 + mt * 16 + g4;
      float4 b4 = *reinterpret_cast<const float4*>(&bb[oq]);
      int h = oq >> 5, d0 = oq & 31;
#pragma unroll
      for (int nt = 0; nt < 4; ++nt) {
        int i = R0 + wn * 64 + nt * 16 + l16;
        int b = i >> 10, n = i & 1023;
        bf16x4 pk;
        pk[0] = (__bf16)(acc[mt][nt][0] + b4.x);
        pk[1] = (__bf16)(acc[mt][nt][1] + b4.y);
        pk[2] = (__bf16)(acc[mt][nt][2] + b4.z);
        pk[3] = (__bf16)(acc[mt][nt][3] + b4.w);
        *reinterpret_cast<bf16x4*>(
            &OWS[(((size_t)b * HEADS + h) * NCTX + n) * DK + d0]) = pk;
      }
    }
  } else {  // V: acc[m=i][n=vo]; pack 4 consecutive n -> b64
#pragma unroll
    for (int nt = 0; nt < 4; ++nt) {
      int vo = (by - 4) * 128 + wn * 64 + nt * 16 + l16;
      float bia = Bias[512 + vo];
#pragma unroll
      for (int mt = 0; mt < 4; ++mt) {
        int i0 = R0 + wm * 64 + mt * 16 + g4;
        int b = i0 >> 10, n = i0 & 1023;
        bf16x4 pk;
#pragma unroll
        for (int rr = 0; rr < 4; ++rr) pk[rr] = (__bf16)(acc[mt][nt][rr] + bia);
        *reinterpret_cast<bf16x4*>(&Vws[((size_t)b * IDV + vo) * NCTX + n]) = pk;
      }
    }
  }
}

// ---------------- out-proj GEMM: 64x64 tiles -> grid 512 (2 blocks/CU) ---------
__global__ __launch_bounds__(256, 4) void k_gemm_out(
    const __bf16* __restrict__ G, const __bf16* __restrict__ WoB,
    const float* __restrict__ bo2, float* __restrict__ out) {
  int bx = blockIdx.x, by = blockIdx.y;   // bx<128, by<4
  int tid = threadIdx.x, wave = tid >> 6, lane = tid & 63;
  int wm = wave >> 1, wn = wave & 1;
  int l16 = lane & 15, g = (lane >> 4) & 3, g4 = g * 4;
  int R0 = bx * 64;

  __shared__ __align__(16) char XTl[8192];   // 64 rows x 64 bf16 (128B rows)
  __shared__ __align__(16) char WTl[8192];   // 64 rows x 64 bf16

  int sr = tid >> 2, sq = tid & 3;
  const __bf16* xg = G + (size_t)(R0 + sr) * IDV + sq * 16;
  const __bf16* wg = WoB + (size_t)(by * 64 + sr) * IDV + sq * 16;
  int sbase = sr * 128;
  int gswq[2];
#pragma unroll
  for (int q = 0; q < 2; ++q) gswq[q] = ((sq * 2 + q) ^ (sr & 7)) * 16;

  bf16x8 sx[2], sw[2];
#pragma unroll
  for (int q = 0; q < 2; ++q) {
    sx[q] = *reinterpret_cast<const bf16x8*>(xg + q * 8);
    sw[q] = *reinterpret_cast<const bf16x8*>(wg + q * 8);
  }

  f32x4 acc[2][2] = {};

  for (int st = 0; st < 8; ++st) {
    __syncthreads();
#pragma unroll
    for (int q = 0; q < 2; ++q) {
      *reinterpret_cast<bf16x8*>(XTl + sbase + gswq[q]) = sx[q];
      *reinterpret_cast<bf16x8*>(WTl + sbase + gswq[q]) = sw[q];
    }
    __syncthreads();
    if (st + 1 < 8) {
      const __bf16* xn = xg + (st + 1) * 64;
      const __bf16* wn_ = wg + (st + 1) * 64;
#pragma unroll
      for (int q = 0; q < 2; ++q) {
        sx[q] = *reinterpret_cast<const bf16x8*>(xn + q * 8);
        sw[q] = *reinterpret_cast<const bf16x8*>(wn_ + q * 8);
      }
    }
#pragma unroll
    for (int kc = 0; kc < 2; ++kc) {
      bf16x8 af[2], bf[2];
#pragma unroll
      for (int t = 0; t < 2; ++t) {
        int ra = wm * 32 + t * 16 + l16;
        af[t] = *reinterpret_cast<const bf16x8*>(
            XTl + ra * 128 + (((kc * 4 + g) ^ (ra & 7)) * 16));
        int rb = wn * 32 + t * 16 + l16;
        bf[t] = *reinterpret_cast<const bf16x8*>(
            WTl + rb * 128 + (((kc * 4 + g) ^ (rb & 7)) * 16));
      }
      __builtin_amdgcn_s_setprio(1);
#pragma unroll
      for (int mt = 0; mt < 2; ++mt)
#pragma unroll
        for (int nt = 0; nt < 2; ++nt)
          acc[mt][nt] = __builtin_amdgcn_mfma_f32_16x16x32_bf16(
              af[mt], bf[nt], acc[mt][nt], 0, 0, 0);
      __builtin_amdgcn_s_setprio(0);
    }
  }
#pragma unroll
  for (int nt = 0; nt < 2; ++nt) {
    int o = by * 64 + wn * 32 + nt * 16 + l16;
    float bia = bo2[o];
#pragma unroll
    for (int mt = 0; mt < 2; ++mt) {
      int i0 = R0 + wm * 32 + mt * 16 + g4;
      int b = i0 >> 10, n = i0 & 1023;
      float4 st;
      st.x = acc[mt][nt][0] + bia;
      st.y = acc[mt][nt][1] + bia;
      st.z = acc[mt][nt][2] + bia;
      st.w = acc[mt][nt][3] + bia;
      *reinterpret_cast<float4*>(&out[((size_t)b * DIM + o) * NCTX + n]) = st;
    }
  }
}

// ---------------- attention: R9 skeleton + tree reductions on critical path ----
// 128 rows/block, 4 waves, K+V LDS dbuf, 1 barrier/iter (best-known structure).
// pmax / ps reductions are pairwise TREES (depth 5) instead of 31-op chains.
__global__ __launch_bounds__(256, 4) void k_attn(
    const __bf16* __restrict__ Qws, const __bf16* __restrict__ Kws,
    const __bf16* __restrict__ Vws, const uint2* __restrict__ Tq4g,
    __bf16* __restrict__ G) {
  int flat = blockIdx.x;                       // 512
  int swz = (flat & 7) * 64 + (flat >> 3);     // XCD-aware: 64 consecutive ids/XCD
  int iblk = swz & 7, bh = swz >> 3;
  int b = bh >> 3, h = bh & 7;
  int tid = threadIdx.x, wave = tid >> 6, lane = tid & 63;
  int l31 = lane & 31, hi = lane >> 5;

  __shared__ __align__(16) __bf16 Klds[2][64][40];
  __shared__ __align__(16) __bf16 Vlds[2][64 * 64];
  __shared__ __align__(16) uint2 TqL[1152];

  int i0b = iblk * 128;
  {
    const uint4* tg4 = reinterpret_cast<const uint4*>(Tq4g + ((size_t)h << 11) + i0b);
    uint4* tl4 = reinterpret_cast<uint4*>(TqL);
    for (int c = tid; c < 576; c += 256) tl4[c] = tg4[c];
  }

  int i0w = i0b + wave * 32;
  int irow = i0w + l31;
  const __bf16* qbase = Qws + (size_t)bh * NCTX * DK;
  const __bf16* kbase = Kws + (size_t)bh * NCTX * DK;
  const __bf16* vbase = Vws + ((size_t)b * IDV + h * DV) * NCTX;
  bf16x8 qf0 = *reinterpret_cast<const bf16x8*>(qbase + (size_t)irow * DK + 8 * hi);
  bf16x8 qf1 = *reinterpret_cast<const bf16x8*>(qbase + (size_t)irow * DK + 16 + 8 * hi);

  // staging map: thread -> K row r_ slot sk (1 granule); V row r_ slots sk, sk+4
  int r_ = tid >> 2, sk = tid & 3;
  const __bf16* kgp = kbase + (size_t)r_ * DK + 8 * sk;
  const __bf16* vgp = vbase + (size_t)r_ * NCTX + 8 * sk;
  int ko = r_ * 40 + 8 * sk;
  int vo0 = r_ * 64 + 8 * (sk ^ (r_ & 7));
  int vo1 = r_ * 64 + 8 * ((sk + 4) ^ (r_ & 7));

  // prologue: tile 0 -> buf 0
  bf16x8 rk = *reinterpret_cast<const bf16x8*>(kgp);
  bf16x8 rv0 = *reinterpret_cast<const bf16x8*>(vgp);
  bf16x8 rv1 = *reinterpret_cast<const bf16x8*>(vgp + 32);
  *reinterpret_cast<bf16x8*>(&Klds[0][0][0] + ko) = rk;
  *reinterpret_cast<bf16x8*>(&Vlds[0][0] + vo0) = rv0;
  *reinterpret_cast<bf16x8*>(&Vlds[0][0] + vo1) = rv1;

  f32x16 acc0 = {}, acc1 = {};
  float m = -1e30f, s = 0.0f;
  int kxb = wave * 32 + l31 + 1023 - 4 * hi;
  const bf16x4* Tqp = reinterpret_cast<const bf16x4*>(TqL);

  __syncthreads();   // buf0 + TqL visible

  for (int it = 0; it < 16; ++it) {
    int cur = it & 1, nxt = cur ^ 1;
    int j0 = it * 64;
    // issue next-tile loads early: they fly across this iteration's compute
    int jn = (j0 + 64) & (NCTX - 1);
    rk = *reinterpret_cast<const bf16x8*>(kgp + (size_t)jn * DK);
    rv0 = *reinterpret_cast<const bf16x8*>(vgp + jn);
    rv1 = *reinterpret_cast<const bf16x8*>(vgp + jn + 32);

    // ---- compute from buf[cur] ----
    float sv[32];
#pragma unroll
    for (int jg = 0; jg < 2; ++jg) {
      bf16x8 kf0 = *reinterpret_cast<const bf16x8*>(&Klds[cur][32 * jg + l31][8 * hi]);
      bf16x8 kf1 = *reinterpret_cast<const bf16x8*>(&Klds[cur][32 * jg + l31][16 + 8 * hi]);
      f32x16 S = {};
      __builtin_amdgcn_s_setprio(1);
      S = __builtin_amdgcn_mfma_f32_32x32x16_bf16(kf0, qf0, S, 0, 0, 0);
      S = __builtin_amdgcn_mfma_f32_32x32x16_bf16(kf1, qf1, S, 0, 0, 0);
      __builtin_amdgcn_s_setprio(0);
      int kb_ = kxb - j0 - 32 * jg;
#pragma unroll
      for (int q = 0; q < 4; ++q) {
        bf16x4 q4 = Tqp[kb_ - 8 * q];
#pragma unroll
        for (int rr = 0; rr < 4; ++rr)
          sv[jg * 16 + q * 4 + rr] = S[q * 4 + rr] + (float)q4[rr];
      }
    }
    // pairwise-tree max (depth 5) instead of serial 31-op chain
    float t16[16];
#pragma unroll
    for (int k = 0; k < 16; ++k) t16[k] = fmaxf(sv[k], sv[k + 16]);
#pragma unroll
    for (int k = 0; k < 8; ++k) t16[k] = fmaxf(t16[k], t16[k + 8]);
#pragma unroll
    for (int k = 0; k < 4; ++k) t16[k] = fmaxf(t16[k], t16[k + 4]);
    float pmax = fmaxf(fmaxf(t16[0], t16[1]), fmaxf(t16[2], t16[3]));
    if (__any(pmax > m + THR)) {   // rare after first tile
      float mx = fmaxf(pmax, __shfl_xor(pmax, 32));
      float mnew = fmaxf(m, mx);
      float corr = __builtin_amdgcn_exp2f(m - mnew);
      s *= corr; m = mnew;
#pragma unroll
      for (int r = 0; r < 16; ++r) {
        float cv = __shfl(corr, (r & 3) + 8 * (r >> 2) + 4 * hi);
        acc0[r] *= cv; acc1[r] *= cv;
      }
    }
#pragma unroll
    for (int k = 0; k < 32; ++k) sv[k] = __builtin_amdgcn_exp2f(sv[k] - m);
    // pairwise-tree sum (depth 5)
    float u16[16];
#pragma unroll
    for (int k = 0; k < 16; ++k) u16[k] = sv[k] + sv[k + 16];
#pragma unroll
    for (int k = 0; k < 8; ++k) u16[k] = u16[k] + u16[k + 8];
#pragma unroll
    for (int k = 0; k < 4; ++k) u16[k] = u16[k] + u16[k + 4];
    s += (u16[0] + u16[1]) + (u16[2] + u16[3]);
#pragma unroll
    for (int jg = 0; jg < 2; ++jg) {
#pragma unroll
      for (int u = 0; u < 2; ++u) {
        int base = jg * 16 + 8 * u;
        unsigned we0, we1, wo0, wo1;
        asm("v_cvt_pk_bf16_f32 %0, %1, %2" : "=v"(we0) : "v"(sv[base + 0]), "v"(sv[base + 1]));
        asm("v_cvt_pk_bf16_f32 %0, %1, %2" : "=v"(we1) : "v"(sv[base + 2]), "v"(sv[base + 3]));
        asm("v_cvt_pk_bf16_f32 %0, %1, %2" : "=v"(wo0) : "v"(sv[base + 4]), "v"(sv[base + 5]));
        asm("v_cvt_pk_bf16_f32 %0, %1, %2" : "=v"(wo1) : "v"(sv[base + 6]), "v"(sv[base + 7]));
        asm volatile("v_permlane32_swap_b32 %0, %1" : "+v"(we0), "+v"(wo0));
        asm volatile("v_permlane32_swap_b32 %0, %1" : "+v"(we1), "+v"(wo1));
        uint4 pw = {we0, we1, wo0, wo1};
        bf16x8 pfrag = *reinterpret_cast<bf16x8*>(&pw);
        int sl = 2 * (jg * 2 + u) + hi;
        bf16x8 vf0 = *reinterpret_cast<const bf16x8*>(
            &Vlds[cur][0] + l31 * 64 + 8 * (sl ^ (l31 & 7)));
        bf16x8 vf1 = *reinterpret_cast<const bf16x8*>(
            &Vlds[cur][0] + (32 + l31) * 64 + 8 * (sl ^ (l31 & 7)));
        __builtin_amdgcn_s_setprio(1);
        acc0 = __builtin_amdgcn_mfma_f32_32x32x16_bf16(pfrag, vf0, acc0, 0, 0, 0);
        acc1 = __builtin_amdgcn_mfma_f32_32x32x16_bf16(pfrag, vf1, acc1, 0, 0, 0);
        __builtin_amdgcn_s_setprio(0);
      }
    }
    // ---- write tile t+1 into buf[nxt] (loads had the whole compute to land) ----
    *reinterpret_cast<bf16x8*>(&Klds[nxt][0][0] + ko) = rk;
    *reinterpret_cast<bf16x8*>(&Vlds[nxt][0] + vo0) = rv0;
    *reinterpret_cast<bf16x8*>(&Vlds[nxt][0] + vo1) = rv1;
    __syncthreads();   // single barrier per iteration
  }
  // epilogue: row-sum across hi halves, /s, exact gelu, store
  float srow = s + __shfl_xor(s, 32);
  float inv = 1.0f / srow;
  __bf16* gbase = G + (size_t)b * NCTX * IDV + h * DV + l31;
#pragma unroll
  for (int r = 0; r < 16; ++r) {
    int il = (r & 3) + 8 * (r >> 2) + 4 * hi;
    float iv = __shfl(inv, il);
    float v0 = acc0[r] * iv, v1 = acc1[r] * iv;
    float g0 = 0.5f * v0 * (1.0f + erff(v0 * 0.70710678118654752f));
    float g1 = 0.5f * v1 * (1.0f + erff(v1 * 0.70710678118654752f));
    gbase[(size_t)(i0w + il) * IDV] = (__bf16)g0;
    gbase[(size_t)(i0w + il) * IDV + 32] = (__bf16)g1;
  }
}

extern "C" void kernel_launch(void* const* d_in, const int* in_sizes, int n_in,
                              void* d_out, int out_size, void* d_ws, size_t ws_size,
                              hipStream_t stream) {
  const float* x  = (const float*)d_in[0];
  const float* Wq = (const float*)d_in[1];
  const float* Wk = (const float*)d_in[2];
  const float* Wv = (const float*)d_in[3];
  const float* Wo = (const float*)d_in[4];
  const float* bo = (const float*)d_in[5];
  const float* pe = (const float*)d_in[6];
  const float* qg = (const float*)d_in[7];
  const float* qb = (const float*)d_in[8];
  const float* qm = (const float*)d_in[9];
  const float* qv = (const float*)d_in[10];
  const float* kg = (const float*)d_in[11];
  const float* kb = (const float*)d_in[12];
  const float* km = (const float*)d_in[13];
  const float* kv = (const float*)d_in[14];
  const float* vg = (const float*)d_in[15];
  const float* vb = (const float*)d_in[16];
  const float* vm = (const float*)d_in[17];
  const float* vv = (const float*)d_in[18];
  const float* og = (const float*)d_in[19];
  const float* ob = (const float*)d_in[20];
  const float* om = (const float*)d_in[21];
  const float* ov = (const float*)d_in[22];

  char* ws = (char*)d_ws;
  __bf16* xT = (__bf16*)(ws);                       // 4 MB
  __bf16* Q  = (__bf16*)(ws + (4ull << 20));        // 4 MB
  __bf16* K  = (__bf16*)(ws + (8ull << 20));        // 4 MB
  __bf16* V  = (__bf16*)(ws + (12ull << 20));       // 8 MB
  __bf16* G  = (__bf16*)(ws + (20ull << 20));       // 8 MB
  __bf16* WB = (__bf16*)(ws + (28ull << 20));       // 768 KB bf16 weights (stacked)
  float*  BB = (float*)(ws + (28ull << 20) + (768ull << 10));  // 5 KB biases
  uint2*  Tq = (uint2*)(ws + (29ull << 20));        // 128 KB bias table
  float* out = (float*)d_out;

  k_prep_trans<<<dim3(2117), 256, 0, stream>>>(
      x, Wq, Wk, Wv, Wo, bo, pe, qg, qb, qm, qv, kg, kb, km, kv,
      vg, vb, vm, vv, og, ob, om, ov, xT, WB, BB, Tq);
  k_gemm_qkv<<<dim3(64, 8), 256, 0, stream>>>(xT, WB, BB, Q, K, V);
  k_attn<<<dim3(512), 256, 0, stream>>>(Q, K, V, Tq, G);
  k_gemm_out<<<dim3(128, 4), 256, 0, stream>>>(G, WB + 262144, BB + 1024, out);
}

// Round 18
// 56.645 us; speedup vs baseline: 1.0137x; 1.0043x over previous
//
#include <hip/hip_runtime.h>
#include <hip/hip_bf16.h>

#define HEADS 8
#define DK 32
#define DV 64
#define DIM 256
#define NCTX 1024
#define NB 8
#define IDK 256
#define IDV 512
#define SCALE 0.17677669529663687f
#define INV_SCALE 5.656854249492381f
#define LOG2E 1.4426950408889634f
#define BN_EPS 1e-5f
#define THR 11.5416f   /* 8 * log2e : defer-max threshold in log2 domain */

typedef __bf16 bf16x8 __attribute__((ext_vector_type(8)));
typedef __bf16 bf16x4 __attribute__((ext_vector_type(4)));
typedef float f32x4 __attribute__((ext_vector_type(4)));
typedef float f32x16 __attribute__((ext_vector_type(16)));

static __device__ __forceinline__ unsigned short bfbits(float v) {
  __bf16 b = (__bf16)v;
  return __builtin_bit_cast(unsigned short, b);
}

// ---------------- prep (weights+bias+bias-table) U transpose ----------------
__global__ __launch_bounds__(256) void k_prep_trans(
    const float* __restrict__ x,
    const float* __restrict__ Wq, const float* __restrict__ Wk,
    const float* __restrict__ Wv, const float* __restrict__ Wo,
    const float* __restrict__ bo, const float* __restrict__ pe,
    const float* __restrict__ qg, const float* __restrict__ qb,
    const float* __restrict__ qm, const float* __restrict__ qv,
    const float* __restrict__ kg, const float* __restrict__ kb,
    const float* __restrict__ km, const float* __restrict__ kv,
    const float* __restrict__ vg, const float* __restrict__ vb,
    const float* __restrict__ vm, const float* __restrict__ vv,
    const float* __restrict__ og, const float* __restrict__ ob,
    const float* __restrict__ om, const float* __restrict__ ov,
    __bf16* __restrict__ xT, __bf16* __restrict__ WB, float* __restrict__ BB,
    uint2* __restrict__ Tq4g) {
  int bid = blockIdx.x;
  if (bid < 1605) {
    int idx = bid * 256 + threadIdx.x;
    if (idx < 65536) {
      int o = idx >> 8;
      WB[idx] = (__bf16)(Wq[idx] * (qg[o] * rsqrtf(qv[o] + BN_EPS) * SCALE * LOG2E));
    } else if (idx < 131072) {
      int i = idx - 65536, o = i >> 8;
      WB[idx] = (__bf16)(Wk[i] * (kg[o] * rsqrtf(kv[o] + BN_EPS)));
    } else if (idx < 262144) {
      int i = idx - 131072, o = i >> 8;
      WB[idx] = (__bf16)(Wv[i] * (vg[o] * rsqrtf(vv[o] + BN_EPS)));
    } else if (idx < 393216) {
      int i = idx - 262144, o = i >> 9;
      WB[idx] = (__bf16)(Wo[i] * (og[o] * rsqrtf(ov[o] + BN_EPS)));
    } else if (idx < 394496) {
      int i = idx - 393216;
      if (i < 256) {
        float sc = qg[i] * rsqrtf(qv[i] + BN_EPS);
        BB[i] = (qb[i] - qm[i] * sc) * SCALE * LOG2E;
      } else if (i < 512) {
        int o = i - 256;
        float sc = kg[o] * rsqrtf(kv[o] + BN_EPS);
        BB[i] = kb[o] - km[o] * sc;
      } else if (i < 1024) {
        int o = i - 512;
        float sc = vg[o] * rsqrtf(vv[o] + BN_EPS);
        BB[i] = vb[o] - vm[o] * sc;
      } else {
        int o = i - 1024;
        float sc = og[o] * rsqrtf(ov[o] + BN_EPS);
        BB[i] = (bo[o] - om[o]) * sc + ob[o];
      }
    } else {
      int i = idx - 394496;          // 8 * 2048 entries
      int h = i >> 11, t = i & 2047;
      unsigned short us[4];
#pragma unroll
      for (int rr = 0; rr < 4; ++rr) {
        int d = t - rr - 1023; d = d < 0 ? -d : d; d = d > 1023 ? 1023 : d;
        us[rr] = bfbits(pe[(size_t)d * HEADS + h] * INV_SCALE * LOG2E);
      }
      uint2 e;
      e.x = (unsigned)us[0] | ((unsigned)us[1] << 16);
      e.y = (unsigned)us[2] | ((unsigned)us[3] << 16);
      Tq4g[((size_t)h << 11) + t] = e;
    }
  } else {
    // transpose x[b,c,n] f32 -> xT[b,n,c] bf16
    __shared__ float t[64][65];
    int tb = bid - 1605;
    int b = tb >> 6, c0 = ((tb >> 4) & 3) * 64, n0 = (tb & 15) * 64;
    int col = threadIdx.x & 63, rb = threadIdx.x >> 6;
    const float* xp = x + ((size_t)b * DIM + c0) * NCTX + n0;
#pragma unroll
    for (int r = 0; r < 16; ++r) {
      int row = rb + 4 * r;
      t[row][col] = xp[(size_t)row * NCTX + col];
    }
    __syncthreads();
    __bf16* op = xT + ((size_t)b * NCTX + n0) * DIM + c0;
#pragma unroll
    for (int r = 0; r < 16; ++r) {
      int i = rb + 4 * r;
      op[(size_t)i * DIM + col] = (__bf16)t[col][i];
    }
  }
}

// ---------------- QKV GEMM: 128x128 block, XOR-swizzled LDS, packed stores ----
__global__ __launch_bounds__(256, 2) void k_gemm_qkv(
    const __bf16* __restrict__ Xsrc, const __bf16* __restrict__ Wsrc,
    const float* __restrict__ Bias, __bf16* __restrict__ Qws,
    __bf16* __restrict__ Kws, __bf16* __restrict__ Vws) {
  int bx = blockIdx.x, by = blockIdx.y;
  int mode = by < 2 ? 0 : (by < 4 ? 1 : 2);
  int tid = threadIdx.x, wave = tid >> 6, lane = tid & 63;
  int wm = wave >> 1, wn = wave & 1;
  int l16 = lane & 15, g = (lane >> 4) & 3, g4 = g * 4;
  int R0 = bx * 128;

  __shared__ __align__(16) char XTl[16384];
  __shared__ __align__(16) char WTl[16384];

  int sr = tid >> 1, sh = tid & 1;
  const __bf16* xg = Xsrc + (size_t)(R0 + sr) * DIM + sh * 32;
  const __bf16* wg = Wsrc + (size_t)(by * 128 + sr) * DIM + sh * 32;
  int wbase = sr * 128;
  int gsw[4];
#pragma unroll
  for (int q = 0; q < 4; ++q) gsw[q] = ((sh * 4 + q) ^ (sr & 7)) * 16;

  bf16x8 sx[4], sw[4];
#pragma unroll
  for (int q = 0; q < 4; ++q) {
    sx[q] = *reinterpret_cast<const bf16x8*>(xg + q * 8);
    sw[q] = *reinterpret_cast<const bf16x8*>(wg + q * 8);
  }

  f32x4 acc[4][4] = {};
  const char* Abase = (mode <= 1) ? WTl : XTl;
  const char* Bbase = (mode <= 1) ? XTl : WTl;

  for (int st = 0; st < 4; ++st) {
    __syncthreads();
#pragma unroll
    for (int q = 0; q < 4; ++q) {
      *reinterpret_cast<bf16x8*>(XTl + wbase + gsw[q]) = sx[q];
      *reinterpret_cast<bf16x8*>(WTl + wbase + gsw[q]) = sw[q];
    }
    __syncthreads();
    if (st + 1 < 4) {
      const __bf16* xn = xg + (st + 1) * 64;
      const __bf16* wn_ = wg + (st + 1) * 64;
#pragma unroll
      for (int q = 0; q < 4; ++q) {
        sx[q] = *reinterpret_cast<const bf16x8*>(xn + q * 8);
        sw[q] = *reinterpret_cast<const bf16x8*>(wn_ + q * 8);
      }
    }
#pragma unroll
    for (int kc = 0; kc < 2; ++kc) {
      bf16x8 af[4], bf[4];
#pragma unroll
      for (int t = 0; t < 4; ++t) {
        int ra = wm * 64 + t * 16 + l16;
        af[t] = *reinterpret_cast<const bf16x8*>(
            Abase + ra * 128 + (((kc * 4 + g) ^ (ra & 7)) * 16));
        int rb = wn * 64 + t * 16 + l16;
        bf[t] = *reinterpret_cast<const bf16x8*>(
            Bbase + rb * 128 + (((kc * 4 + g) ^ (rb & 7)) * 16));
      }
      __builtin_amdgcn_s_setprio(1);
#pragma unroll
      for (int mt = 0; mt < 4; ++mt)
#pragma unroll
        for (int nt = 0; nt < 4; ++nt)
          acc[mt][nt] = __builtin_amdgcn_mfma_f32_16x16x32_bf16(
              af[mt], bf[nt], acc[mt][nt], 0, 0, 0);
      __builtin_amdgcn_s_setprio(0);
    }
  }

  if (mode <= 1) {  // Q/K: acc[m=o][n=i]; pack 4 consecutive d -> b64
    __bf16* OWS = (mode == 0) ? Qws : Kws;
    const float* bb = Bias + (mode == 0 ? 0 : 256);
    int oq0 = by * 128 - (mode == 1 ? 256 : 0) + wm * 64;
#pragma unroll
    for (int mt = 0; mt < 4; ++mt) {
      int oq = oq0 + mt * 16 + g4;
      float4 b4 = *reinterpret_cast<const float4*>(&bb[oq]);
      int h = oq >> 5, d0 = oq & 31;
#pragma unroll
      for (int nt = 0; nt < 4; ++nt) {
        int i = R0 + wn * 64 + nt * 16 + l16;
        int b = i >> 10, n = i & 1023;
        bf16x4 pk;
        pk[0] = (__bf16)(acc[mt][nt][0] + b4.x);
        pk[1] = (__bf16)(acc[mt][nt][1] + b4.y);
        pk[2] = (__bf16)(acc[mt][nt][2] + b4.z);
        pk[3] = (__bf16)(acc[mt][nt][3] + b4.w);
        *reinterpret_cast<bf16x4*>(
            &OWS[(((size_t)b * HEADS + h) * NCTX + n) * DK + d0]) = pk;
      }
    }
  } else {  // V: acc[m=i][n=vo]; pack 4 consecutive n -> b64
#pragma unroll
    for (int nt = 0; nt < 4; ++nt) {
      int vo = (by - 4) * 128 + wn * 64 + nt * 16 + l16;
      float bia = Bias[512 + vo];
#pragma unroll
      for (int mt = 0; mt < 4; ++mt) {
        int i0 = R0 + wm * 64 + mt * 16 + g4;
        int b = i0 >> 10, n = i0 & 1023;
        bf16x4 pk;
#pragma unroll
        for (int rr = 0; rr < 4; ++rr) pk[rr] = (__bf16)(acc[mt][nt][rr] + bia);
        *reinterpret_cast<bf16x4*>(&Vws[((size_t)b * IDV + vo) * NCTX + n]) = pk;
      }
    }
  }
}

// ---------------- out-proj GEMM: 64x64 tiles -> grid 512 (2 blocks/CU) ---------
__global__ __launch_bounds__(256, 4) void k_gemm_out(
    const __bf16* __restrict__ G, const __bf16* __restrict__ WoB,
    const float* __restrict__ bo2, float* __restrict__ out) {
  int bx = blockIdx.x, by = blockIdx.y;   // bx<128, by<4
  int tid = threadIdx.x, wave = tid >> 6, lane = tid & 63;
  int wm = wave >> 1, wn = wave & 1;
  int l16 = lane & 15, g = (lane >> 4) & 3, g4 = g * 4;
  int R0 = bx * 64;

  __shared__ __align__(16) char XTl[8192];   // 64 rows x 64 bf16 (128B rows)
  __shared__ __align__(16) char WTl[8192];   // 64 rows x 64 bf16

  int sr = tid >> 2, sq = tid & 3;
  const __bf16* xg = G + (size_t)(R0 + sr) * IDV + sq * 16;
  const __bf16* wg = WoB + (size_t)(by * 64 + sr) * IDV + sq * 16;
  int sbase = sr * 128;
  int gswq[2];
#pragma unroll
  for (int q = 0; q < 2; ++q) gswq[q] = ((sq * 2 + q) ^ (sr & 7)) * 16;

  bf16x8 sx[2], sw[2];
#pragma unroll
  for (int q = 0; q < 2; ++q) {
    sx[q] = *reinterpret_cast<const bf16x8*>(xg + q * 8);
    sw[q] = *reinterpret_cast<const bf16x8*>(wg + q * 8);
  }

  f32x4 acc[2][2] = {};

  for (int st = 0; st < 8; ++st) {
    __syncthreads();
#pragma unroll
    for (int q = 0; q < 2; ++q) {
      *reinterpret_cast<bf16x8*>(XTl + sbase + gswq[q]) = sx[q];
      *reinterpret_cast<bf16x8*>(WTl + sbase + gswq[q]) = sw[q];
    }
    __syncthreads();
    if (st + 1 < 8) {
      const __bf16* xn = xg + (st + 1) * 64;
      const __bf16* wn_ = wg + (st + 1) * 64;
#pragma unroll
      for (int q = 0; q < 2; ++q) {
        sx[q] = *reinterpret_cast<const bf16x8*>(xn + q * 8);
        sw[q] = *reinterpret_cast<const bf16x8*>(wn_ + q * 8);
      }
    }
#pragma unroll
    for (int kc = 0; kc < 2; ++kc) {
      bf16x8 af[2], bf[2];
#pragma unroll
      for (int t = 0; t < 2; ++t) {
        int ra = wm * 32 + t * 16 + l16;
        af[t] = *reinterpret_cast<const bf16x8*>(
            XTl + ra * 128 + (((kc * 4 + g) ^ (ra & 7)) * 16));
        int rb = wn * 32 + t * 16 + l16;
        bf[t] = *reinterpret_cast<const bf16x8*>(
            WTl + rb * 128 + (((kc * 4 + g) ^ (rb & 7)) * 16));
      }
      __builtin_amdgcn_s_setprio(1);
#pragma unroll
      for (int mt = 0; mt < 2; ++mt)
#pragma unroll
        for (int nt = 0; nt < 2; ++nt)
          acc[mt][nt] = __builtin_amdgcn_mfma_f32_16x16x32_bf16(
              af[mt], bf[nt], acc[mt][nt], 0, 0, 0);
      __builtin_amdgcn_s_setprio(0);
    }
  }
#pragma unroll
  for (int nt = 0; nt < 2; ++nt) {
    int o = by * 64 + wn * 32 + nt * 16 + l16;
    float bia = bo2[o];
#pragma unroll
    for (int mt = 0; mt < 2; ++mt) {
      int i0 = R0 + wm * 32 + mt * 16 + g4;
      int b = i0 >> 10, n = i0 & 1023;
      float4 st;
      st.x = acc[mt][nt][0] + bia;
      st.y = acc[mt][nt][1] + bia;
      st.z = acc[mt][nt][2] + bia;
      st.w = acc[mt][nt][3] + bia;
      *reinterpret_cast<float4*>(&out[((size_t)b * DIM + o) * NCTX + n]) = st;
    }
  }
}

// ---------------- attention: R15 skeleton + 2-deep register prefetch -----------
// 128 rows/block, 4 waves, K+V LDS dbuf, 1 barrier/iter. Loads for tile t+2
// issued at iteration t; ds_write uses data loaded a FULL iteration earlier
// (~2 compute phases of latency slack -> pre-write waitcnt never stalls).
// Two named register sets alternated statically via x2-unrolled body.
__global__ __launch_bounds__(256, 3) void k_attn(
    const __bf16* __restrict__ Qws, const __bf16* __restrict__ Kws,
    const __bf16* __restrict__ Vws, const uint2* __restrict__ Tq4g,
    __bf16* __restrict__ G) {
  int flat = blockIdx.x;                       // 512
  int swz = (flat & 7) * 64 + (flat >> 3);     // XCD-aware: 64 consecutive ids/XCD
  int iblk = swz & 7, bh = swz >> 3;
  int b = bh >> 3, h = bh & 7;
  int tid = threadIdx.x, wave = tid >> 6, lane = tid & 63;
  int l31 = lane & 31, hi = lane >> 5;

  __shared__ __align__(16) __bf16 Klds[2][64][40];
  __shared__ __align__(16) __bf16 Vlds[2][64 * 64];
  __shared__ __align__(16) uint2 TqL[1152];

  int i0b = iblk * 128;
  {
    const uint4* tg4 = reinterpret_cast<const uint4*>(Tq4g + ((size_t)h << 11) + i0b);
    uint4* tl4 = reinterpret_cast<uint4*>(TqL);
    for (int c = tid; c < 576; c += 256) tl4[c] = tg4[c];
  }

  int i0w = i0b + wave * 32;
  int irow = i0w + l31;
  const __bf16* qbase = Qws + (size_t)bh * NCTX * DK;
  const __bf16* kbase = Kws + (size_t)bh * NCTX * DK;
  const __bf16* vbase = Vws + ((size_t)b * IDV + h * DV) * NCTX;
  bf16x8 qf0 = *reinterpret_cast<const bf16x8*>(qbase + (size_t)irow * DK + 8 * hi);
  bf16x8 qf1 = *reinterpret_cast<const bf16x8*>(qbase + (size_t)irow * DK + 16 + 8 * hi);

  // staging map: thread -> K row r_ slot sk (1 granule); V row r_ slots sk, sk+4
  int r_ = tid >> 2, sk = tid & 3;
  const __bf16* kgp = kbase + (size_t)r_ * DK + 8 * sk;
  const __bf16* vgp = vbase + (size_t)r_ * NCTX + 8 * sk;
  int ko = r_ * 40 + 8 * sk;
  int vo0 = r_ * 64 + 8 * (sk ^ (r_ & 7));
  int vo1 = r_ * 64 + 8 * ((sk + 4) ^ (r_ & 7));

  f32x16 acc0 = {}, acc1 = {};
  float m = -1e30f, s = 0.0f;
  int kxb = wave * 32 + l31 + 1023 - 4 * hi;
  const bf16x4* Tqp = reinterpret_cast<const bf16x4*>(TqL);

  // prologue: tile 0 -> buf 0 (immediate); tile 1 -> register set A (held)
  {
    bf16x8 t0k = *reinterpret_cast<const bf16x8*>(kgp);
    bf16x8 t0v0 = *reinterpret_cast<const bf16x8*>(vgp);
    bf16x8 t0v1 = *reinterpret_cast<const bf16x8*>(vgp + 32);
    *reinterpret_cast<bf16x8*>(&Klds[0][0][0] + ko) = t0k;
    *reinterpret_cast<bf16x8*>(&Vlds[0][0] + vo0) = t0v0;
    *reinterpret_cast<bf16x8*>(&Vlds[0][0] + vo1) = t0v1;
  }
  bf16x8 kA = *reinterpret_cast<const bf16x8*>(kgp + (size_t)64 * DK);
  bf16x8 v0A = *reinterpret_cast<const bf16x8*>(vgp + 64);
  bf16x8 v1A = *reinterpret_cast<const bf16x8*>(vgp + 96);
  bf16x8 kB, v0B, v1B;

  __syncthreads();   // buf0 + TqL visible

  // COMPUTE body for one 64-j tile from buf[CUR]
#define ATTN_STEP(CUR, J0)                                                        \
  {                                                                               \
    float sv[32];                                                                 \
    _Pragma("unroll")                                                             \
    for (int jg = 0; jg < 2; ++jg) {                                              \
      bf16x8 kf0 = *reinterpret_cast<const bf16x8*>(                              \
          &Klds[CUR][32 * jg + l31][8 * hi]);                                     \
      bf16x8 kf1 = *reinterpret_cast<const bf16x8*>(                              \
          &Klds[CUR][32 * jg + l31][16 + 8 * hi]);                                \
      f32x16 S = {};                                                              \
      __builtin_amdgcn_s_setprio(1);                                              \
      S = __builtin_amdgcn_mfma_f32_32x32x16_bf16(kf0, qf0, S, 0, 0, 0);          \
      S = __builtin_amdgcn_mfma_f32_32x32x16_bf16(kf1, qf1, S, 0, 0, 0);          \
      __builtin_amdgcn_s_setprio(0);                                              \
      int kb_ = kxb - (J0) - 32 * jg;                                             \
      _Pragma("unroll")                                                           \
      for (int q = 0; q < 4; ++q) {                                               \
        bf16x4 q4 = Tqp[kb_ - 8 * q];                                             \
        _Pragma("unroll")                                                         \
        for (int rr = 0; rr < 4; ++rr)                                            \
          sv[jg * 16 + q * 4 + rr] = S[q * 4 + rr] + (float)q4[rr];               \
      }                                                                           \
    }                                                                             \
    float pmax = sv[0];                                                           \
    _Pragma("unroll")                                                             \
    for (int k = 1; k < 32; ++k) pmax = fmaxf(pmax, sv[k]);                       \
    if (__any(pmax > m + THR)) {                                                  \
      float mx = fmaxf(pmax, __shfl_xor(pmax, 32));                               \
      float mnew = fmaxf(m, mx);                                                  \
      float corr = __builtin_amdgcn_exp2f(m - mnew);                              \
      s *= corr; m = mnew;                                                        \
      _Pragma("unroll")                                                           \
      for (int r = 0; r < 16; ++r) {                                              \
        float cv = __shfl(corr, (r & 3) + 8 * (r >> 2) + 4 * hi);                 \
        acc0[r] *= cv; acc1[r] *= cv;                                             \
      }                                                                           \
    }                                                                             \
    _Pragma("unroll")                                                             \
    for (int k = 0; k < 32; ++k) sv[k] = __builtin_amdgcn_exp2f(sv[k] - m);       \
    float ps = 0.0f;                                                              \
    _Pragma("unroll")                                                             \
    for (int k = 0; k < 32; ++k) ps += sv[k];                                     \
    s += ps;                                                                      \
    _Pragma("unroll")                                                             \
    for (int jg = 0; jg < 2; ++jg) {                                              \
      _Pragma("unroll")                                                           \
      for (int u = 0; u < 2; ++u) {                                               \
        int base = jg * 16 + 8 * u;                                               \
        unsigned we0, we1, wo0, wo1;                                              \
        asm("v_cvt_pk_bf16_f32 %0, %1, %2"                                        \
            : "=v"(we0) : "v"(sv[base + 0]), "v"(sv[base + 1]));                  \
        asm("v_cvt_pk_bf16_f32 %0, %1, %2"                                        \
            : "=v"(we1) : "v"(sv[base + 2]), "v"(sv[base + 3]));                  \
        asm("v_cvt_pk_bf16_f32 %0, %1, %2"                                        \
            : "=v"(wo0) : "v"(sv[base + 4]), "v"(sv[base + 5]));                  \
        asm("v_cvt_pk_bf16_f32 %0, %1, %2"                                        \
            : "=v"(wo1) : "v"(sv[base + 6]), "v"(sv[base + 7]));                  \
        asm volatile("v_permlane32_swap_b32 %0, %1" : "+v"(we0), "+v"(wo0));      \
        asm volatile("v_permlane32_swap_b32 %0, %1" : "+v"(we1), "+v"(wo1));      \
        uint4 pw = {we0, we1, wo0, wo1};                                          \
        bf16x8 pfrag = *reinterpret_cast<bf16x8*>(&pw);                           \
        int sl = 2 * (jg * 2 + u) + hi;                                           \
        bf16x8 vf0 = *reinterpret_cast<const bf16x8*>(                            \
            &Vlds[CUR][0] + l31 * 64 + 8 * (sl ^ (l31 & 7)));                     \
        bf16x8 vf1 = *reinterpret_cast<const bf16x8*>(                            \
            &Vlds[CUR][0] + (32 + l31) * 64 + 8 * (sl ^ (l31 & 7)));              \
        __builtin_amdgcn_s_setprio(1);                                            \
        acc0 = __builtin_amdgcn_mfma_f32_32x32x16_bf16(pfrag, vf0, acc0, 0,0,0);  \
        acc1 = __builtin_amdgcn_mfma_f32_32x32x16_bf16(pfrag, vf1, acc1, 0,0,0);  \
        __builtin_amdgcn_s_setprio(0);                                            \
      }                                                                           \
    }                                                                             \
  }

  for (int it2 = 0; it2 < 8; ++it2) {
    int t = it2 * 2;
    // ---- iteration t: cur=0, nxt=1; issue loads for tile t+2 -> set B ----
    {
      int jn = ((t + 2) * 64) & (NCTX - 1);
      kB = *reinterpret_cast<const bf16x8*>(kgp + (size_t)jn * DK);
      v0B = *reinterpret_cast<const bf16x8*>(vgp + jn);
      v1B = *reinterpret_cast<const bf16x8*>(vgp + jn + 32);
      ATTN_STEP(0, t * 64);
      // write tile t+1 (set A, loaded a full iteration ago) -> buf 1
      *reinterpret_cast<bf16x8*>(&Klds[1][0][0] + ko) = kA;
      *reinterpret_cast<bf16x8*>(&Vlds[1][0] + vo0) = v0A;
      *reinterpret_cast<bf16x8*>(&Vlds[1][0] + vo1) = v1A;
      __syncthreads();
    }
    // ---- iteration t+1: cur=1, nxt=0; issue loads for tile t+3 -> set A ----
    {
      int jn = ((t + 3) * 64) & (NCTX - 1);
      kA = *reinterpret_cast<const bf16x8*>(kgp + (size_t)jn * DK);
      v0A = *reinterpret_cast<const bf16x8*>(vgp + jn);
      v1A = *reinterpret_cast<const bf16x8*>(vgp + jn + 32);
      ATTN_STEP(1, (t + 1) * 64);
      // write tile t+2 (set B) -> buf 0
      *reinterpret_cast<bf16x8*>(&Klds[0][0][0] + ko) = kB;
      *reinterpret_cast<bf16x8*>(&Vlds[0][0] + vo0) = v0B;
      *reinterpret_cast<bf16x8*>(&Vlds[0][0] + vo1) = v1B;
      __syncthreads();
    }
  }
#undef ATTN_STEP

  // epilogue: row-sum across hi halves, /s, exact gelu, store
  float srow = s + __shfl_xor(s, 32);
  float inv = 1.0f / srow;
  __bf16* gbase = G + (size_t)b * NCTX * IDV + h * DV + l31;
#pragma unroll
  for (int r = 0; r < 16; ++r) {
    int il = (r & 3) + 8 * (r >> 2) + 4 * hi;
    float iv = __shfl(inv, il);
    float v0 = acc0[r] * iv, v1 = acc1[r] * iv;
    float g0 = 0.5f * v0 * (1.0f + erff(v0 * 0.70710678118654752f));
    float g1 = 0.5f * v1 * (1.0f + erff(v1 * 0.70710678118654752f));
    gbase[(size_t)(i0w + il) * IDV] = (__bf16)g0;
    gbase[(size_t)(i0w + il) * IDV + 32] = (__bf16)g1;
  }
}

extern "C" void kernel_launch(void* const* d_in, const int* in_sizes, int n_in,
                              void* d_out, int out_size, void* d_ws, size_t ws_size,
                              hipStream_t stream) {
  const float* x  = (const float*)d_in[0];
  const float* Wq = (const float*)d_in[1];
  const float* Wk = (const float*)d_in[2];
  const float* Wv = (const float*)d_in[3];
  const float* Wo = (const float*)d_in[4];
  const float* bo = (const float*)d_in[5];
  const float* pe = (const float*)d_in[6];
  const float* qg = (const float*)d_in[7];
  const float* qb = (const float*)d_in[8];
  const float* qm = (const float*)d_in[9];
  const float* qv = (const float*)d_in[10];
  const float* kg = (const float*)d_in[11];
  const float* kb = (const float*)d_in[12];
  const float* km = (const float*)d_in[13];
  const float* kv = (const float*)d_in[14];
  const float* vg = (const float*)d_in[15];
  const float* vb = (const float*)d_in[16];
  const float* vm = (const float*)d_in[17];
  const float* vv = (const float*)d_in[18];
  const float* og = (const float*)d_in[19];
  const float* ob = (const float*)d_in[20];
  const float* om = (const float*)d_in[21];
  const float* ov = (const float*)d_in[22];

  char* ws = (char*)d_ws;
  __bf16* xT = (__bf16*)(ws);                       // 4 MB
  __bf16* Q  = (__bf16*)(ws + (4ull << 20));        // 4 MB
  __bf16* K  = (__bf16*)(ws + (8ull << 20));        // 4 MB
  __bf16* V  = (__bf16*)(ws + (12ull << 20));       // 8 MB
  __bf16* G  = (__bf16*)(ws + (20ull << 20));       // 8 MB
  __bf16* WB = (__bf16*)(ws + (28ull << 20));       // 768 KB bf16 weights (stacked)
  float*  BB = (float*)(ws + (28ull << 20) + (768ull << 10));  // 5 KB biases
  uint2*  Tq = (uint2*)(ws + (29ull << 20));        // 128 KB bias table
  float* out = (float*)d_out;

  k_prep_trans<<<dim3(2117), 256, 0, stream>>>(
      x, Wq, Wk, Wv, Wo, bo, pe, qg, qb, qm, qv, kg, kb, km, kv,
      vg, vb, vm, vv, og, ob, om, ov, xT, WB, BB, Tq);
  k_gemm_qkv<<<dim3(64, 8), 256, 0, stream>>>(xT, WB, BB, Q, K, V);
  k_attn<<<dim3(512), 256, 0, stream>>>(Q, K, V, Tq, G);
  k_gemm_out<<<dim3(128, 4), 256, 0, stream>>>(G, WB + 262144, BB + 1024, out);
}